// Round 5
// baseline (229.528 us; speedup 1.0000x reference)
//
#include <hip/hip_runtime.h>

typedef unsigned int  uint;
typedef unsigned short ushort;

#define N_PTS  1048576
#define BLOCK  256
#define WAVES  4
#define NPT    2
#define CHUNK  (WAVES * NPT * 16)     // 128 points per block-iteration
#define NCHUNK (N_PTS / CHUNK)        // 8192
#define GRID   2048                   // 8 blocks/CU target (LDS 128/160 KB)

static_assert(N_PTS % CHUNK == 0, "chunking");
static_assert(NCHUNK % GRID == 0, "grid stride");

typedef __attribute__((ext_vector_type(8))) __bf16  bf16x8;
typedef __attribute__((ext_vector_type(2))) __bf16  bf16x2;
typedef __attribute__((ext_vector_type(4))) float   f32x4;

struct Params {
    const float* emb[3];
    const float* views;
    const float* mask[3];
    const float* w[21];
    float* out;
};

// Pre-arranged bf16 A-fragment weight blob, written by prep_weights each call.
__device__ uint g_wbuf[3 * 9216];

// per-branch weight blob layout (u16 offsets into g_wbuf viewed as ushort*)
#define OFF_S0 0
#define OFF_S1 2048
#define OFF_S2 6144
#define OFF_C0 7168
#define OFF_C1 9216
#define OFF_C2 13312
#define OFF_C3 17408
#define BR_SZ  18432

// f32 pair -> packed bf16x2 (compiler emits v_cvt_pk_bf16_f32, RNE)
__device__ __forceinline__ uint cvt2(float a, float b) {
    bf16x2 v = {(__bf16)a, (__bf16)b};
    return __builtin_bit_cast(uint, v);
}

__device__ __forceinline__ f32x4 MFMA(bf16x8 a, bf16x8 b, f32x4 c) {
    return __builtin_amdgcn_mfma_f32_16x16x32_bf16(a, b, c, 0, 0, 0);
}

__device__ __forceinline__ float fast_rcp(float x) { return __builtin_amdgcn_rcpf(x); }

// Swizzled pointer into a 16x64-bf16 activation tile (2048 B, row stride 128 B).
__device__ __forceinline__ ushort* actp(ushort* buf, int c, int f) {
    int byte = (c << 7) + (f << 1);
    byte ^= (c & 7) << 4;
    return (ushort*)((char*)buf + byte);
}

// weight element fetch with layer-specific remapping (see R1 notes).
__device__ __forceinline__ float wval(int kind, const float* W, int k, int m) {
    switch (kind) {
        default:
        case 0: return W[k * 64 + m];
        case 1: return W[k * 17 + (m == 0 ? 0 : m + 1)];
        case 2: { int r = (k >= 1 && k <= 15) ? (k + 2) : ((k >= 16 && k <= 18) ? (k - 16) : -1);
                  return (r < 0) ? 0.f : W[r * 64 + m]; }
        case 3: { int r = (k >= 1 && k <= 15) ? (k - 1) : -1;
                  return (r < 0) ? 0.f : W[r * 64 + m]; }
        case 4: return (m < 3) ? W[k * 3 + m] : 0.f;
    }
}

// ------------------- prologue: arrange weights as A-fragments -------------------
__global__ void prep_weights(Params P) {
    const int idx = blockIdx.x * 256 + threadIdx.x;   // 0 .. 27647
    const int br  = idx / 9216;
    const int rem = idx - br * 9216;
    int L, q;
    if      (rem < 1024) { L = 0; q = rem;        }
    else if (rem < 3072) { L = 1; q = rem - 1024; }
    else if (rem < 3584) { L = 2; q = rem - 3072; }
    else if (rem < 4608) { L = 3; q = rem - 3584; }
    else if (rem < 6656) { L = 4; q = rem - 4608; }
    else if (rem < 8704) { L = 5; q = rem - 6656; }
    else                 { L = 6; q = rem - 8704; }
    const float* W   = P.w[br * 7 + L];
    const int kk_n   = (L == 0 || L == 3) ? 1 : 2;
    const int kind   = (L == 2) ? 1 : (L == 3) ? (br == 0 ? 2 : 3) : (L == 6) ? 4 : 0;
    const int E  = q * 2;
    const int b  = E >> 9;
    const int ln = (E >> 3) & 63;
    const int e  = E & 7;
    const int mt = b / kk_n;
    const int kk = b - mt * kk_n;
    const int m  = mt * 16 + (ln & 15);
    const int k  = kk * 32 + (ln >> 4) * 8 + e;
    g_wbuf[idx] = cvt2(wval(kind, W, k, m), wval(kind, W, k + 1, m));
}

// hidden 64->64 layer with relu, NPT tiles; weights read straight from global blob
__device__ __forceinline__ void layer_h64(const ushort* lw, int lane,
                                          ushort* const (&rd0)[NPT],
                                          ushort* const (&rd1)[NPT],
                                          ushort* const (&wr)[NPT][4]) {
    bf16x8 wf[8];
#pragma unroll
    for (int b = 0; b < 8; ++b) wf[b] = *(const bf16x8*)(lw + b * 512 + lane * 8);
#pragma unroll
    for (int t = 0; t < NPT; ++t) {
        const bf16x8 i0 = *(const bf16x8*)rd0[t];
        const bf16x8 i1 = *(const bf16x8*)rd1[t];
        f32x4 acc[4];
#pragma unroll
        for (int mt = 0; mt < 4; ++mt) {
            acc[mt] = (f32x4){0.f, 0.f, 0.f, 0.f};
            acc[mt] = MFMA(wf[mt * 2 + 0], i0, acc[mt]);
            acc[mt] = MFMA(wf[mt * 2 + 1], i1, acc[mt]);
        }
#pragma unroll
        for (int mt = 0; mt < 4; ++mt) {
            uint2 o;
            o.x = cvt2(fmaxf(acc[mt][0], 0.f), fmaxf(acc[mt][1], 0.f));
            o.y = cvt2(fmaxf(acc[mt][2], 0.f), fmaxf(acc[mt][3], 0.f));
            *(uint2*)wr[t][mt] = o;
        }
    }
}

__global__ __launch_bounds__(BLOCK, 4) void nerf_main(Params P) {
    __shared__ __align__(16) ushort lds_act[WAVES][NPT][1024]; // 16 KB act tiles only

    const int tid  = threadIdx.x;
    const int wave = tid >> 6;
    const int lane = tid & 63;
    const int c = lane & 15;   // point within tile
    const int g = lane >> 4;   // lane group
    const ushort* gw = (const ushort*)g_wbuf;

    // hoisted swizzled LDS addresses (loop-invariant per lane)
    ushort* rd0[NPT]; ushort* rd1[NPT]; ushort* wr[NPT][4];
#pragma unroll
    for (int t = 0; t < NPT; ++t) {
        ushort* base = lds_act[wave][t];
        rd0[t] = actp(base, c, g * 8);
        rd1[t] = actp(base, c, 32 + g * 8);
#pragma unroll
        for (int mt = 0; mt < 4; ++mt) wr[t][mt] = actp(base, c, mt * 16 + g * 4);
    }

#pragma unroll 1
    for (int ch = blockIdx.x; ch < NCHUNK; ch += gridDim.x) {
        const int p0 = ch * CHUNK + wave * (NPT * 16);

        float stot[NPT], car[NPT], cag[NPT], cab[NPT];
#pragma unroll
        for (int t = 0; t < NPT; ++t) { stot[t] = 0.f; car[t] = 0.f; cag[t] = 0.f; cab[t] = 0.f; }

#pragma unroll 1
        for (int br = 0; br < 3; ++br) {
            const ushort* lw  = gw + br * BR_SZ;
            const float* emb  = P.emb[br];
            const float* msk  = P.mask[br];
            float sig_pre[NPT], rp[NPT], gp[NPT], bp[NPT];

            // ---- sigma L0 : emb(32) -> 64, relu
            {
                bf16x8 wf[4];
#pragma unroll
                for (int b = 0; b < 4; ++b)
                    wf[b] = *(const bf16x8*)(lw + OFF_S0 + b * 512 + lane * 8);
#pragma unroll
                for (int t = 0; t < NPT; ++t) {
                    const float* ep = emb + (size_t)(p0 + t * 16 + c) * 32 + g * 8;
                    const float4 ea = *(const float4*)ep;
                    const float4 eb = *(const float4*)(ep + 4);
                    uint4 iv;
                    iv.x = cvt2(ea.x, ea.y); iv.y = cvt2(ea.z, ea.w);
                    iv.z = cvt2(eb.x, eb.y); iv.w = cvt2(eb.z, eb.w);
                    const bf16x8 inf = __builtin_bit_cast(bf16x8, iv);
                    f32x4 acc[4];
#pragma unroll
                    for (int mt = 0; mt < 4; ++mt) {
                        acc[mt] = (f32x4){0.f, 0.f, 0.f, 0.f};
                        acc[mt] = MFMA(wf[mt], inf, acc[mt]);
                    }
#pragma unroll
                    for (int mt = 0; mt < 4; ++mt) {
                        uint2 o;
                        o.x = cvt2(fmaxf(acc[mt][0], 0.f), fmaxf(acc[mt][1], 0.f));
                        o.y = cvt2(fmaxf(acc[mt][2], 0.f), fmaxf(acc[mt][3], 0.f));
                        *(uint2*)wr[t][mt] = o;
                    }
                }
            }

            // ---- sigma L1 : 64 -> 64, relu
            layer_h64(lw + OFF_S1, lane, rd0, rd1, wr);

            // ---- sigma L2 : 64 -> 16 [f0=sigma-pre, f1..15=geo], raw; zero f16..31
            {
                const bf16x8 w0 = *(const bf16x8*)(lw + OFF_S2 + 0 * 512 + lane * 8);
                const bf16x8 w1 = *(const bf16x8*)(lw + OFF_S2 + 1 * 512 + lane * 8);
#pragma unroll
                for (int t = 0; t < NPT; ++t) {
                    const bf16x8 i0 = *(const bf16x8*)rd0[t];
                    const bf16x8 i1 = *(const bf16x8*)rd1[t];
                    f32x4 acc = (f32x4){0.f, 0.f, 0.f, 0.f};
                    acc = MFMA(w0, i0, acc);
                    acc = MFMA(w1, i1, acc);
                    sig_pre[t] = acc[0];  // valid in lanes 0..15 (feature 0)
                    uint2 o;
                    o.x = cvt2(acc[0], acc[1]);
                    o.y = cvt2(acc[2], acc[3]);
                    *(uint2*)wr[t][0] = o;
                    const uint2 z = {0u, 0u};
                    *(uint2*)wr[t][1] = z;
                }
            }

            // ---- color L0 : feats[0..31] -> 64, relu (bg: views patched at k=16..18)
            {
                bf16x8 wf[4];
#pragma unroll
                for (int b = 0; b < 4; ++b)
                    wf[b] = *(const bf16x8*)(lw + OFF_C0 + b * 512 + lane * 8);
#pragma unroll
                for (int t = 0; t < NPT; ++t) {
                    bf16x8 inf = *(const bf16x8*)rd0[t];
                    if (br == 0 && g == 2) {
                        const float* vp = P.views + (size_t)(p0 + t * 16 + c) * 3;
                        uint4 iv;
                        iv.x = cvt2(vp[0], vp[1]);
                        iv.y = cvt2(vp[2], 0.f);
                        iv.z = 0u; iv.w = 0u;
                        inf = __builtin_bit_cast(bf16x8, iv);
                    }
                    f32x4 acc[4];
#pragma unroll
                    for (int mt = 0; mt < 4; ++mt) {
                        acc[mt] = (f32x4){0.f, 0.f, 0.f, 0.f};
                        acc[mt] = MFMA(wf[mt], inf, acc[mt]);
                    }
#pragma unroll
                    for (int mt = 0; mt < 4; ++mt) {
                        uint2 o;
                        o.x = cvt2(fmaxf(acc[mt][0], 0.f), fmaxf(acc[mt][1], 0.f));
                        o.y = cvt2(fmaxf(acc[mt][2], 0.f), fmaxf(acc[mt][3], 0.f));
                        *(uint2*)wr[t][mt] = o;
                    }
                }
            }

            // ---- color L1, L2 : 64 -> 64, relu
            layer_h64(lw + OFF_C1, lane, rd0, rd1, wr);
            layer_h64(lw + OFF_C2, lane, rd0, rd1, wr);

            // ---- color L3 : 64 -> rgb (features 0..2, lanes 0..15)
            {
                const bf16x8 w0 = *(const bf16x8*)(lw + OFF_C3 + 0 * 512 + lane * 8);
                const bf16x8 w1 = *(const bf16x8*)(lw + OFF_C3 + 1 * 512 + lane * 8);
#pragma unroll
                for (int t = 0; t < NPT; ++t) {
                    const bf16x8 i0 = *(const bf16x8*)rd0[t];
                    const bf16x8 i1 = *(const bf16x8*)rd1[t];
                    f32x4 acc = (f32x4){0.f, 0.f, 0.f, 0.f};
                    acc = MFMA(w0, i0, acc);
                    acc = MFMA(w1, i1, acc);
                    rp[t] = acc[0]; gp[t] = acc[1]; bp[t] = acc[2];
                }
            }

            // ---- branch epilogue: softplus/sigmoid/mask via v_exp/v_log/v_rcp
#pragma unroll
            for (int t = 0; t < NPT; ++t) {
                const float mk = msk[p0 + t * 16 + c];
                const float x  = sig_pre[t];
                const float ex = __expf(x);
                const float sp = (x > 15.f) ? x : 0.69314718f * __log2f(1.f + ex);
                const float sb = sp * mk;
                stot[t] += sb;
                const float sm = sb * mk;
                car[t] += sm * fast_rcp(1.f + __expf(-rp[t]));
                cag[t] += sm * fast_rcp(1.f + __expf(-gp[t]));
                cab[t] += sm * fast_rcp(1.f + __expf(-bp[t]));
            }
        }

        // ---- final blend + store (lanes 0..15 hold the per-point values)
#pragma unroll
        for (int t = 0; t < NPT; ++t) {
            if (lane < 16) {
                const float s   = stot[t] + 1e-9f;
                const float inv = fast_rcp(s);
                float4 o;
                o.x = car[t] * inv; o.y = cag[t] * inv; o.z = cab[t] * inv; o.w = s;
                *(float4*)(P.out + (size_t)(p0 + t * 16 + lane) * 4) = o;
            }
        }
    }
}

extern "C" void kernel_launch(void* const* d_in, const int* in_sizes, int n_in,
                              void* d_out, int out_size, void* d_ws, size_t ws_size,
                              hipStream_t stream) {
    (void)in_sizes; (void)n_in; (void)d_ws; (void)ws_size; (void)out_size;
    Params P;
    P.emb[0] = (const float*)d_in[0];   // embedded_xyz      (bg)
    P.emb[1] = (const float*)d_in[1];   // embedded_xyzt     (fg)
    P.emb[2] = (const float*)d_in[2];   // embedded_xyzt_cam (actor)
    P.views  = (const float*)d_in[3];
    P.mask[0] = (const float*)d_in[4];
    P.mask[1] = (const float*)d_in[5];
    P.mask[2] = (const float*)d_in[6];
    for (int i = 0; i < 21; ++i) P.w[i] = (const float*)d_in[7 + i];
    P.out = (float*)d_out;
    prep_weights<<<108, 256, 0, stream>>>(P);   // 27648 threads, one u32 word each
    nerf_main<<<GRID, BLOCK, 0, stream>>>(P);
}

// Round 6
// 191.285 us; speedup vs baseline: 1.1999x; 1.1999x over previous
//
#include <hip/hip_runtime.h>

typedef unsigned int  uint;
typedef unsigned short ushort;

#define N_PTS  1048576
#define BLOCK  256
#define WAVES  4
#define NPT    4
#define CHUNK  (WAVES * NPT * 16)     // 256 points per block-iteration
#define NCHUNK (N_PTS / CHUNK)        // 4096
#define GRID   2048                   // 2 chunk-iterations per block

static_assert(N_PTS % CHUNK == 0, "chunking");
static_assert(NCHUNK % GRID == 0, "grid stride");

typedef __attribute__((ext_vector_type(8))) __bf16  bf16x8;
typedef __attribute__((ext_vector_type(2))) __bf16  bf16x2;
typedef __attribute__((ext_vector_type(4))) float   f32x4;

struct Params {
    const float* emb[3];
    const float* views;
    const float* mask[3];
    const float* w[21];
    float* out;
};

// Pre-arranged bf16 A-fragment weight blob, written by prep_weights each call.
__device__ uint g_wbuf[3 * 9216];

// per-branch weight blob layout (u16 offsets into g_wbuf viewed as ushort*)
#define OFF_S0 0
#define OFF_S1 2048
#define OFF_S2 6144
#define OFF_C0 7168
#define OFF_C1 9216
#define OFF_C2 13312
#define OFF_C3 17408
#define BR_SZ  18432

// f32 pair -> packed bf16x2 (compiler emits v_cvt_pk_bf16_f32, RNE)
__device__ __forceinline__ uint cvt2(float a, float b) {
    bf16x2 v = {(__bf16)a, (__bf16)b};
    return __builtin_bit_cast(uint, v);
}

__device__ __forceinline__ f32x4 MFMA(bf16x8 a, bf16x8 b, f32x4 c) {
    return __builtin_amdgcn_mfma_f32_16x16x32_bf16(a, b, c, 0, 0, 0);
}

__device__ __forceinline__ float fast_rcp(float x) { return __builtin_amdgcn_rcpf(x); }

// weight element fetch with layer-specific remapping (see R1 notes).
__device__ __forceinline__ float wval(int kind, const float* W, int k, int m) {
    switch (kind) {
        default:
        case 0: return W[k * 64 + m];
        case 1: return W[k * 17 + (m == 0 ? 0 : m + 1)];
        case 2: { int r = (k >= 1 && k <= 15) ? (k + 2) : ((k >= 16 && k <= 18) ? (k - 16) : -1);
                  return (r < 0) ? 0.f : W[r * 64 + m]; }
        case 3: { int r = (k >= 1 && k <= 15) ? (k - 1) : -1;
                  return (r < 0) ? 0.f : W[r * 64 + m]; }
        case 4: return (m < 3) ? W[k * 3 + m] : 0.f;
    }
}

// ------------------- prologue: arrange weights as A-fragments -------------------
__global__ void prep_weights(Params P) {
    const int idx = blockIdx.x * 256 + threadIdx.x;   // 0 .. 27647
    const int br  = idx / 9216;
    const int rem = idx - br * 9216;
    int L, q;
    if      (rem < 1024) { L = 0; q = rem;        }
    else if (rem < 3072) { L = 1; q = rem - 1024; }
    else if (rem < 3584) { L = 2; q = rem - 3072; }
    else if (rem < 4608) { L = 3; q = rem - 3584; }
    else if (rem < 6656) { L = 4; q = rem - 4608; }
    else if (rem < 8704) { L = 5; q = rem - 6656; }
    else                 { L = 6; q = rem - 8704; }
    const float* W   = P.w[br * 7 + L];
    const int kk_n   = (L == 0 || L == 3) ? 1 : 2;
    const int kind   = (L == 2) ? 1 : (L == 3) ? (br == 0 ? 2 : 3) : (L == 6) ? 4 : 0;
    const int E  = q * 2;
    const int b  = E >> 9;
    const int ln = (E >> 3) & 63;
    const int e  = E & 7;
    const int mt = b / kk_n;
    const int kk = b - mt * kk_n;
    const int m  = mt * 16 + (ln & 15);
    const int k  = kk * 32 + (ln >> 4) * 8 + e;
    g_wbuf[idx] = cvt2(wval(kind, W, k, m), wval(kind, W, k + 1, m));
}

// hidden 64->64 layer with relu, NPT tiles; weights read straight from global blob.
// Tile t lives at +t*1024 ushorts from the lane-constant swizzled base pointers
// (the t-offset folds into the ds-instruction immediate).
__device__ __forceinline__ void layer_h64(const ushort* lw, int lane,
                                          const ushort* rd0b, const ushort* rd1b,
                                          ushort* const (&wrb)[4]) {
    bf16x8 wf[8];
#pragma unroll
    for (int b = 0; b < 8; ++b) wf[b] = *(const bf16x8*)(lw + b * 512 + lane * 8);
#pragma unroll
    for (int t = 0; t < NPT; ++t) {
        const bf16x8 i0 = *(const bf16x8*)(rd0b + t * 1024);
        const bf16x8 i1 = *(const bf16x8*)(rd1b + t * 1024);
        f32x4 acc[4];
#pragma unroll
        for (int mt = 0; mt < 4; ++mt) {
            acc[mt] = (f32x4){0.f, 0.f, 0.f, 0.f};
            acc[mt] = MFMA(wf[mt * 2 + 0], i0, acc[mt]);
            acc[mt] = MFMA(wf[mt * 2 + 1], i1, acc[mt]);
        }
#pragma unroll
        for (int mt = 0; mt < 4; ++mt) {
            uint2 o;
            o.x = cvt2(fmaxf(acc[mt][0], 0.f), fmaxf(acc[mt][1], 0.f));
            o.y = cvt2(fmaxf(acc[mt][2], 0.f), fmaxf(acc[mt][3], 0.f));
            *(uint2*)(wrb[mt] + t * 1024) = o;
        }
    }
}

__global__ __launch_bounds__(BLOCK, 4) void nerf_main(Params P) {
    __shared__ __align__(16) ushort lds_act[WAVES][NPT][1024]; // 32 KB act tiles

    const int tid  = threadIdx.x;
    const int wave = tid >> 6;
    const int lane = tid & 63;
    const int c = lane & 15;   // point within tile
    const int g = lane >> 4;   // lane group
    const ushort* gw = (const ushort*)g_wbuf;

    // lane-constant swizzled base pointers into tile 0 of this wave
    ushort* base = lds_act[wave][0];
    const int sw = (c & 7) << 4;                       // byte-XOR swizzle
    auto offu = [&](int f) { return ((c << 7) + (((f << 1)) ^ sw)) >> 1; };  // ushort units
    const ushort* rd0b = base + offu(g * 8);
    const ushort* rd1b = base + offu(32 + g * 8);
    ushort* wrb[4];
#pragma unroll
    for (int mt = 0; mt < 4; ++mt) wrb[mt] = base + offu(mt * 16 + g * 4);

    const int rot = blockIdx.x % 3;                    // branch-rotation phase

#pragma unroll 1
    for (int ch = blockIdx.x; ch < NCHUNK; ch += gridDim.x) {
        const int p0 = ch * CHUNK + wave * (NPT * 16);

        float stot[NPT], car[NPT], cag[NPT], cab[NPT];
#pragma unroll
        for (int t = 0; t < NPT; ++t) { stot[t] = 0.f; car[t] = 0.f; cag[t] = 0.f; cab[t] = 0.f; }

#pragma unroll 1
        for (int bi = 0; bi < 3; ++bi) {
            int br = rot + bi; if (br >= 3) br -= 3;
            const ushort* lw  = gw + br * BR_SZ;
            const float* emb  = P.emb[br];
            const float* msk  = P.mask[br];
            float sig_pre[NPT], rp[NPT], gp[NPT], bp[NPT];

            // ---- sigma L0 : emb(32) -> 64, relu
            {
                bf16x8 wf[4];
#pragma unroll
                for (int b = 0; b < 4; ++b)
                    wf[b] = *(const bf16x8*)(lw + OFF_S0 + b * 512 + lane * 8);
#pragma unroll
                for (int t = 0; t < NPT; ++t) {
                    const float* ep = emb + (size_t)(p0 + t * 16 + c) * 32 + g * 8;
                    const float4 ea = *(const float4*)ep;
                    const float4 eb = *(const float4*)(ep + 4);
                    uint4 iv;
                    iv.x = cvt2(ea.x, ea.y); iv.y = cvt2(ea.z, ea.w);
                    iv.z = cvt2(eb.x, eb.y); iv.w = cvt2(eb.z, eb.w);
                    const bf16x8 inf = __builtin_bit_cast(bf16x8, iv);
                    f32x4 acc[4];
#pragma unroll
                    for (int mt = 0; mt < 4; ++mt) {
                        acc[mt] = (f32x4){0.f, 0.f, 0.f, 0.f};
                        acc[mt] = MFMA(wf[mt], inf, acc[mt]);
                    }
#pragma unroll
                    for (int mt = 0; mt < 4; ++mt) {
                        uint2 o;
                        o.x = cvt2(fmaxf(acc[mt][0], 0.f), fmaxf(acc[mt][1], 0.f));
                        o.y = cvt2(fmaxf(acc[mt][2], 0.f), fmaxf(acc[mt][3], 0.f));
                        *(uint2*)(wrb[mt] + t * 1024) = o;
                    }
                }
            }

            // ---- sigma L1 : 64 -> 64, relu
            layer_h64(lw + OFF_S1, lane, rd0b, rd1b, wrb);

            // ---- sigma L2 : 64 -> 16 [f0=sigma-pre, f1..15=geo], raw; zero f16..31
            {
                const bf16x8 w0 = *(const bf16x8*)(lw + OFF_S2 + 0 * 512 + lane * 8);
                const bf16x8 w1 = *(const bf16x8*)(lw + OFF_S2 + 1 * 512 + lane * 8);
#pragma unroll
                for (int t = 0; t < NPT; ++t) {
                    const bf16x8 i0 = *(const bf16x8*)(rd0b + t * 1024);
                    const bf16x8 i1 = *(const bf16x8*)(rd1b + t * 1024);
                    f32x4 acc = (f32x4){0.f, 0.f, 0.f, 0.f};
                    acc = MFMA(w0, i0, acc);
                    acc = MFMA(w1, i1, acc);
                    sig_pre[t] = acc[0];  // valid in lanes 0..15 (feature 0)
                    uint2 o;
                    o.x = cvt2(acc[0], acc[1]);
                    o.y = cvt2(acc[2], acc[3]);
                    *(uint2*)(wrb[0] + t * 1024) = o;
                    const uint2 z = {0u, 0u};
                    *(uint2*)(wrb[1] + t * 1024) = z;
                }
            }

            // ---- color L0 : feats[0..31] -> 64, relu (bg: views patched at k=16..18)
            {
                bf16x8 wf[4];
#pragma unroll
                for (int b = 0; b < 4; ++b)
                    wf[b] = *(const bf16x8*)(lw + OFF_C0 + b * 512 + lane * 8);
#pragma unroll
                for (int t = 0; t < NPT; ++t) {
                    bf16x8 inf = *(const bf16x8*)(rd0b + t * 1024);
                    if (br == 0 && g == 2) {
                        const float* vp = P.views + (size_t)(p0 + t * 16 + c) * 3;
                        uint4 iv;
                        iv.x = cvt2(vp[0], vp[1]);
                        iv.y = cvt2(vp[2], 0.f);
                        iv.z = 0u; iv.w = 0u;
                        inf = __builtin_bit_cast(bf16x8, iv);
                    }
                    f32x4 acc[4];
#pragma unroll
                    for (int mt = 0; mt < 4; ++mt) {
                        acc[mt] = (f32x4){0.f, 0.f, 0.f, 0.f};
                        acc[mt] = MFMA(wf[mt], inf, acc[mt]);
                    }
#pragma unroll
                    for (int mt = 0; mt < 4; ++mt) {
                        uint2 o;
                        o.x = cvt2(fmaxf(acc[mt][0], 0.f), fmaxf(acc[mt][1], 0.f));
                        o.y = cvt2(fmaxf(acc[mt][2], 0.f), fmaxf(acc[mt][3], 0.f));
                        *(uint2*)(wrb[mt] + t * 1024) = o;
                    }
                }
            }

            // ---- color L1, L2 : 64 -> 64, relu
            layer_h64(lw + OFF_C1, lane, rd0b, rd1b, wrb);
            layer_h64(lw + OFF_C2, lane, rd0b, rd1b, wrb);

            // ---- color L3 : 64 -> rgb (features 0..2, lanes 0..15)
            {
                const bf16x8 w0 = *(const bf16x8*)(lw + OFF_C3 + 0 * 512 + lane * 8);
                const bf16x8 w1 = *(const bf16x8*)(lw + OFF_C3 + 1 * 512 + lane * 8);
#pragma unroll
                for (int t = 0; t < NPT; ++t) {
                    const bf16x8 i0 = *(const bf16x8*)(rd0b + t * 1024);
                    const bf16x8 i1 = *(const bf16x8*)(rd1b + t * 1024);
                    f32x4 acc = (f32x4){0.f, 0.f, 0.f, 0.f};
                    acc = MFMA(w0, i0, acc);
                    acc = MFMA(w1, i1, acc);
                    rp[t] = acc[0]; gp[t] = acc[1]; bp[t] = acc[2];
                }
            }

            // ---- branch epilogue: softplus/sigmoid/mask via v_exp/v_log/v_rcp
#pragma unroll
            for (int t = 0; t < NPT; ++t) {
                const float mk = msk[p0 + t * 16 + c];
                const float x  = sig_pre[t];
                const float ex = __expf(x);
                const float sp = (x > 15.f) ? x : 0.69314718f * __log2f(1.f + ex);
                const float sb = sp * mk;
                stot[t] += sb;
                const float sm = sb * mk;
                car[t] += sm * fast_rcp(1.f + __expf(-rp[t]));
                cag[t] += sm * fast_rcp(1.f + __expf(-gp[t]));
                cab[t] += sm * fast_rcp(1.f + __expf(-bp[t]));
            }
        }

        // ---- final blend + store (lanes 0..15 hold the per-point values)
#pragma unroll
        for (int t = 0; t < NPT; ++t) {
            if (lane < 16) {
                const float s   = stot[t] + 1e-9f;
                const float inv = fast_rcp(s);
                float4 o;
                o.x = car[t] * inv; o.y = cag[t] * inv; o.z = cab[t] * inv; o.w = s;
                *(float4*)(P.out + (size_t)(p0 + t * 16 + lane) * 4) = o;
            }
        }
    }
}

extern "C" void kernel_launch(void* const* d_in, const int* in_sizes, int n_in,
                              void* d_out, int out_size, void* d_ws, size_t ws_size,
                              hipStream_t stream) {
    (void)in_sizes; (void)n_in; (void)d_ws; (void)ws_size; (void)out_size;
    Params P;
    P.emb[0] = (const float*)d_in[0];   // embedded_xyz      (bg)
    P.emb[1] = (const float*)d_in[1];   // embedded_xyzt     (fg)
    P.emb[2] = (const float*)d_in[2];   // embedded_xyzt_cam (actor)
    P.views  = (const float*)d_in[3];
    P.mask[0] = (const float*)d_in[4];
    P.mask[1] = (const float*)d_in[5];
    P.mask[2] = (const float*)d_in[6];
    for (int i = 0; i < 21; ++i) P.w[i] = (const float*)d_in[7 + i];
    P.out = (float*)d_out;
    prep_weights<<<108, 256, 0, stream>>>(P);   // 27648 threads, one u32 word each
    nerf_main<<<GRID, BLOCK, 0, stream>>>(P);
}

// Round 7
// 184.548 us; speedup vs baseline: 1.2437x; 1.0365x over previous
//
#include <hip/hip_runtime.h>

typedef unsigned int  uint;
typedef unsigned short ushort;

#define N_PTS  1048576
#define BLOCK  768
#define WAVES  12
#define NPT    2
#define CHUNK  (WAVES * NPT * 16)     // 384 points per block-iteration
#define NCHUNK ((N_PTS + CHUNK - 1) / CHUNK)   // 2731 (last partial)
#define GRID   256                    // 1 block/CU (LDS 156 KB)

typedef __attribute__((ext_vector_type(8))) __bf16  bf16x8;
typedef __attribute__((ext_vector_type(2))) __bf16  bf16x2;
typedef __attribute__((ext_vector_type(4))) float   f32x4;

struct Params {
    const float* emb[3];
    const float* views;
    const float* mask[3];
    const float* w[21];
    float* out;
};

// Pre-arranged bf16 A-fragment weight blob, written by prep_weights each call.
__device__ uint g_wbuf[3 * 9216];

// per-branch weight blob layout (u16 offsets)
#define OFF_S0 0
#define OFF_S1 2048
#define OFF_S2 6144
#define OFF_C0 7168
#define OFF_C1 9216
#define OFF_C2 13312
#define OFF_C3 17408
#define BR_SZ  18432

// f32 pair -> packed bf16x2 (compiler emits v_cvt_pk_bf16_f32, RNE)
__device__ __forceinline__ uint cvt2(float a, float b) {
    bf16x2 v = {(__bf16)a, (__bf16)b};
    return __builtin_bit_cast(uint, v);
}

__device__ __forceinline__ f32x4 MFMA(bf16x8 a, bf16x8 b, f32x4 c) {
    return __builtin_amdgcn_mfma_f32_16x16x32_bf16(a, b, c, 0, 0, 0);
}

__device__ __forceinline__ float fast_rcp(float x) { return __builtin_amdgcn_rcpf(x); }

// weight element fetch with layer-specific remapping (see R1 notes).
__device__ __forceinline__ float wval(int kind, const float* W, int k, int m) {
    switch (kind) {
        default:
        case 0: return W[k * 64 + m];
        case 1: return W[k * 17 + (m == 0 ? 0 : m + 1)];
        case 2: { int r = (k >= 1 && k <= 15) ? (k + 2) : ((k >= 16 && k <= 18) ? (k - 16) : -1);
                  return (r < 0) ? 0.f : W[r * 64 + m]; }
        case 3: { int r = (k >= 1 && k <= 15) ? (k - 1) : -1;
                  return (r < 0) ? 0.f : W[r * 64 + m]; }
        case 4: return (m < 3) ? W[k * 3 + m] : 0.f;
    }
}

// ------------------- prologue: arrange weights as A-fragments -------------------
__global__ void prep_weights(Params P) {
    const int idx = blockIdx.x * 256 + threadIdx.x;   // 0 .. 27647
    const int br  = idx / 9216;
    const int rem = idx - br * 9216;
    int L, q;
    if      (rem < 1024) { L = 0; q = rem;        }
    else if (rem < 3072) { L = 1; q = rem - 1024; }
    else if (rem < 3584) { L = 2; q = rem - 3072; }
    else if (rem < 4608) { L = 3; q = rem - 3584; }
    else if (rem < 6656) { L = 4; q = rem - 4608; }
    else if (rem < 8704) { L = 5; q = rem - 6656; }
    else                 { L = 6; q = rem - 8704; }
    const float* W   = P.w[br * 7 + L];
    const int kk_n   = (L == 0 || L == 3) ? 1 : 2;
    const int kind   = (L == 2) ? 1 : (L == 3) ? (br == 0 ? 2 : 3) : (L == 6) ? 4 : 0;
    const int E  = q * 2;
    const int b  = E >> 9;
    const int ln = (E >> 3) & 63;
    const int e  = E & 7;
    const int mt = b / kk_n;
    const int kk = b - mt * kk_n;
    const int m  = mt * 16 + (ln & 15);
    const int k  = kk * 32 + (ln >> 4) * 8 + e;
    g_wbuf[idx] = cvt2(wval(kind, W, k, m), wval(kind, W, k + 1, m));
}

// hidden 64->64 layer with relu, NPT tiles; weights read from LDS fragments.
__device__ __forceinline__ void layer_h64(const ushort* lw, int lane,
                                          const ushort* rd0b, const ushort* rd1b,
                                          ushort* const (&wrb)[4]) {
    bf16x8 wf[8];
#pragma unroll
    for (int b = 0; b < 8; ++b) wf[b] = *(const bf16x8*)(lw + b * 512 + lane * 8);
#pragma unroll
    for (int t = 0; t < NPT; ++t) {
        const bf16x8 i0 = *(const bf16x8*)(rd0b + t * 1024);
        const bf16x8 i1 = *(const bf16x8*)(rd1b + t * 1024);
        f32x4 acc[4];
#pragma unroll
        for (int mt = 0; mt < 4; ++mt) {
            acc[mt] = (f32x4){0.f, 0.f, 0.f, 0.f};
            acc[mt] = MFMA(wf[mt * 2 + 0], i0, acc[mt]);
            acc[mt] = MFMA(wf[mt * 2 + 1], i1, acc[mt]);
        }
#pragma unroll
        for (int mt = 0; mt < 4; ++mt) {
            uint2 o;
            o.x = cvt2(fmaxf(acc[mt][0], 0.f), fmaxf(acc[mt][1], 0.f));
            o.y = cvt2(fmaxf(acc[mt][2], 0.f), fmaxf(acc[mt][3], 0.f));
            *(uint2*)(wrb[mt] + t * 1024) = o;
        }
    }
}

__global__ __launch_bounds__(BLOCK, 3) void nerf_main(Params P) {
    __shared__ __align__(16) ushort lds_w[3 * BR_SZ];            // 108 KB weights
    __shared__ __align__(16) ushort lds_act[WAVES][NPT][1024];   // 48 KB act tiles

    const int tid  = threadIdx.x;

    // ---- stage pre-arranged weight blob global -> LDS, once per block ----
    {
        const uint4* src = (const uint4*)g_wbuf;     // 6912 uint4
        uint4* dst = (uint4*)lds_w;
#pragma unroll
        for (int k = 0; k < 9; ++k)
            dst[tid + k * BLOCK] = src[tid + k * BLOCK];
    }
    __syncthreads();

    const int wave = tid >> 6;
    const int lane = tid & 63;
    const int c = lane & 15;   // point within tile
    const int g = lane >> 4;   // lane group

    // lane-constant swizzled base pointers into tile 0 of this wave
    ushort* base = lds_act[wave][0];
    const int sw = (c & 7) << 4;                       // byte-XOR swizzle
    auto offu = [&](int f) { return ((c << 7) + (((f << 1)) ^ sw)) >> 1; };  // ushort units
    const ushort* rd0b = base + offu(g * 8);
    const ushort* rd1b = base + offu(32 + g * 8);
    ushort* wrb[4];
#pragma unroll
    for (int mt = 0; mt < 4; ++mt) wrb[mt] = base + offu(mt * 16 + g * 4);

#pragma unroll 1
    for (int ch = blockIdx.x; ch < NCHUNK; ch += gridDim.x) {
        const int p0 = ch * CHUNK + wave * (NPT * 16);

        float stot[NPT], car[NPT], cag[NPT], cab[NPT];
#pragma unroll
        for (int t = 0; t < NPT; ++t) { stot[t] = 0.f; car[t] = 0.f; cag[t] = 0.f; cab[t] = 0.f; }

#pragma unroll 1
        for (int br = 0; br < 3; ++br) {
            const ushort* lw  = lds_w + br * BR_SZ;
            const float* emb  = P.emb[br];
            const float* msk  = P.mask[br];
            float sig_pre[NPT], rp[NPT], gp[NPT], bp[NPT];

            // ---- sigma L0 : emb(32) -> 64, relu (clamped point index)
            {
                bf16x8 wf[4];
#pragma unroll
                for (int b = 0; b < 4; ++b)
                    wf[b] = *(const bf16x8*)(lw + OFF_S0 + b * 512 + lane * 8);
#pragma unroll
                for (int t = 0; t < NPT; ++t) {
                    int pi = p0 + t * 16 + c;
                    pi = pi < N_PTS ? pi : N_PTS - 1;
                    const float* ep = emb + (size_t)pi * 32 + g * 8;
                    const float4 ea = *(const float4*)ep;
                    const float4 eb = *(const float4*)(ep + 4);
                    uint4 iv;
                    iv.x = cvt2(ea.x, ea.y); iv.y = cvt2(ea.z, ea.w);
                    iv.z = cvt2(eb.x, eb.y); iv.w = cvt2(eb.z, eb.w);
                    const bf16x8 inf = __builtin_bit_cast(bf16x8, iv);
                    f32x4 acc[4];
#pragma unroll
                    for (int mt = 0; mt < 4; ++mt) {
                        acc[mt] = (f32x4){0.f, 0.f, 0.f, 0.f};
                        acc[mt] = MFMA(wf[mt], inf, acc[mt]);
                    }
#pragma unroll
                    for (int mt = 0; mt < 4; ++mt) {
                        uint2 o;
                        o.x = cvt2(fmaxf(acc[mt][0], 0.f), fmaxf(acc[mt][1], 0.f));
                        o.y = cvt2(fmaxf(acc[mt][2], 0.f), fmaxf(acc[mt][3], 0.f));
                        *(uint2*)(wrb[mt] + t * 1024) = o;
                    }
                }
            }

            // ---- sigma L1 : 64 -> 64, relu
            layer_h64(lw + OFF_S1, lane, rd0b, rd1b, wrb);

            // ---- sigma L2 : 64 -> 16 [f0=sigma-pre, f1..15=geo], raw; zero f16..31
            {
                const bf16x8 w0 = *(const bf16x8*)(lw + OFF_S2 + 0 * 512 + lane * 8);
                const bf16x8 w1 = *(const bf16x8*)(lw + OFF_S2 + 1 * 512 + lane * 8);
#pragma unroll
                for (int t = 0; t < NPT; ++t) {
                    const bf16x8 i0 = *(const bf16x8*)(rd0b + t * 1024);
                    const bf16x8 i1 = *(const bf16x8*)(rd1b + t * 1024);
                    f32x4 acc = (f32x4){0.f, 0.f, 0.f, 0.f};
                    acc = MFMA(w0, i0, acc);
                    acc = MFMA(w1, i1, acc);
                    sig_pre[t] = acc[0];  // valid in lanes 0..15 (feature 0)
                    uint2 o;
                    o.x = cvt2(acc[0], acc[1]);
                    o.y = cvt2(acc[2], acc[3]);
                    *(uint2*)(wrb[0] + t * 1024) = o;
                    const uint2 z = {0u, 0u};
                    *(uint2*)(wrb[1] + t * 1024) = z;
                }
            }

            // ---- color L0 : feats[0..31] -> 64, relu (bg: views patched at k=16..18)
            {
                bf16x8 wf[4];
#pragma unroll
                for (int b = 0; b < 4; ++b)
                    wf[b] = *(const bf16x8*)(lw + OFF_C0 + b * 512 + lane * 8);
#pragma unroll
                for (int t = 0; t < NPT; ++t) {
                    bf16x8 inf = *(const bf16x8*)(rd0b + t * 1024);
                    if (br == 0 && g == 2) {
                        int pi = p0 + t * 16 + c;
                        pi = pi < N_PTS ? pi : N_PTS - 1;
                        const float* vp = P.views + (size_t)pi * 3;
                        uint4 iv;
                        iv.x = cvt2(vp[0], vp[1]);
                        iv.y = cvt2(vp[2], 0.f);
                        iv.z = 0u; iv.w = 0u;
                        inf = __builtin_bit_cast(bf16x8, iv);
                    }
                    f32x4 acc[4];
#pragma unroll
                    for (int mt = 0; mt < 4; ++mt) {
                        acc[mt] = (f32x4){0.f, 0.f, 0.f, 0.f};
                        acc[mt] = MFMA(wf[mt], inf, acc[mt]);
                    }
#pragma unroll
                    for (int mt = 0; mt < 4; ++mt) {
                        uint2 o;
                        o.x = cvt2(fmaxf(acc[mt][0], 0.f), fmaxf(acc[mt][1], 0.f));
                        o.y = cvt2(fmaxf(acc[mt][2], 0.f), fmaxf(acc[mt][3], 0.f));
                        *(uint2*)(wrb[mt] + t * 1024) = o;
                    }
                }
            }

            // ---- color L1, L2 : 64 -> 64, relu
            layer_h64(lw + OFF_C1, lane, rd0b, rd1b, wrb);
            layer_h64(lw + OFF_C2, lane, rd0b, rd1b, wrb);

            // ---- color L3 : 64 -> rgb (features 0..2, lanes 0..15)
            {
                const bf16x8 w0 = *(const bf16x8*)(lw + OFF_C3 + 0 * 512 + lane * 8);
                const bf16x8 w1 = *(const bf16x8*)(lw + OFF_C3 + 1 * 512 + lane * 8);
#pragma unroll
                for (int t = 0; t < NPT; ++t) {
                    const bf16x8 i0 = *(const bf16x8*)(rd0b + t * 1024);
                    const bf16x8 i1 = *(const bf16x8*)(rd1b + t * 1024);
                    f32x4 acc = (f32x4){0.f, 0.f, 0.f, 0.f};
                    acc = MFMA(w0, i0, acc);
                    acc = MFMA(w1, i1, acc);
                    rp[t] = acc[0]; gp[t] = acc[1]; bp[t] = acc[2];
                }
            }

            // ---- branch epilogue: softplus/sigmoid/mask via v_exp/v_log/v_rcp
#pragma unroll
            for (int t = 0; t < NPT; ++t) {
                int pi = p0 + t * 16 + c;
                pi = pi < N_PTS ? pi : N_PTS - 1;
                const float mk = msk[pi];
                const float x  = sig_pre[t];
                const float ex = __expf(x);
                const float sp = (x > 15.f) ? x : 0.69314718f * __log2f(1.f + ex);
                const float sb = sp * mk;
                stot[t] += sb;
                const float sm = sb * mk;
                car[t] += sm * fast_rcp(1.f + __expf(-rp[t]));
                cag[t] += sm * fast_rcp(1.f + __expf(-gp[t]));
                cab[t] += sm * fast_rcp(1.f + __expf(-bp[t]));
            }
        }

        // ---- final blend + store (lanes 0..15 hold the per-point values)
#pragma unroll
        for (int t = 0; t < NPT; ++t) {
            const int pq = p0 + t * 16 + lane;
            if (lane < 16 && pq < N_PTS) {
                const float s   = stot[t] + 1e-9f;
                const float inv = fast_rcp(s);
                float4 o;
                o.x = car[t] * inv; o.y = cag[t] * inv; o.z = cab[t] * inv; o.w = s;
                *(float4*)(P.out + (size_t)pq * 4) = o;
            }
        }
    }
}

extern "C" void kernel_launch(void* const* d_in, const int* in_sizes, int n_in,
                              void* d_out, int out_size, void* d_ws, size_t ws_size,
                              hipStream_t stream) {
    (void)in_sizes; (void)n_in; (void)d_ws; (void)ws_size; (void)out_size;
    Params P;
    P.emb[0] = (const float*)d_in[0];   // embedded_xyz      (bg)
    P.emb[1] = (const float*)d_in[1];   // embedded_xyzt     (fg)
    P.emb[2] = (const float*)d_in[2];   // embedded_xyzt_cam (actor)
    P.views  = (const float*)d_in[3];
    P.mask[0] = (const float*)d_in[4];
    P.mask[1] = (const float*)d_in[5];
    P.mask[2] = (const float*)d_in[6];
    for (int i = 0; i < 21; ++i) P.w[i] = (const float*)d_in[7 + i];
    P.out = (float*)d_out;
    prep_weights<<<108, 256, 0, stream>>>(P);   // 27648 threads, one u32 word each
    nerf_main<<<GRID, BLOCK, 0, stream>>>(P);
}

// Round 8
// 178.287 us; speedup vs baseline: 1.2874x; 1.0351x over previous
//
#include <hip/hip_runtime.h>

typedef unsigned int  uint;
typedef unsigned short ushort;

#define N_PTS  1048576
#define BLOCK  1024
#define WAVES  16
#define NPT    2
#define CHUNK  (WAVES * NPT * 16)     // 512 points per block-iteration
#define NCHUNK (N_PTS / CHUNK)        // 2048, exact
#define GRID   256                    // 1 block/CU, 16 waves/CU

static_assert(N_PTS % CHUNK == 0, "chunking");
static_assert(NCHUNK % GRID == 0, "grid stride");

typedef __attribute__((ext_vector_type(8))) __bf16  bf16x8;
typedef __attribute__((ext_vector_type(2))) __bf16  bf16x2;
typedef __attribute__((ext_vector_type(4))) float   f32x4;

struct Params {
    const float* emb[3];
    const float* views;
    const float* mask[3];
    const float* w[21];
    float* out;
};

// Pre-arranged bf16 A-fragment weight blob, written by prep_weights each call.
__device__ uint g_wbuf[3 * 9216];

// per-branch weight blob layout (u16 offsets)
#define OFF_S0 0
#define OFF_S1 2048
#define OFF_S2 6144
#define OFF_C0 7168
#define OFF_C1 9216
#define OFF_C2 13312
#define OFF_C3 17408
#define BR_SZ  18432

// f32 pair -> packed bf16x2 (compiler emits v_cvt_pk_bf16_f32, RNE)
__device__ __forceinline__ uint cvt2(float a, float b) {
    bf16x2 v = {(__bf16)a, (__bf16)b};
    return __builtin_bit_cast(uint, v);
}

__device__ __forceinline__ f32x4 MFMA(bf16x8 a, bf16x8 b, f32x4 c) {
    return __builtin_amdgcn_mfma_f32_16x16x32_bf16(a, b, c, 0, 0, 0);
}

__device__ __forceinline__ float fast_rcp(float x) { return __builtin_amdgcn_rcpf(x); }

// permlane swaps: P32: a'=[a.g0,a.g1,b.g0,b.g1], b'=[a.g2,a.g3,b.g2,b.g3]
//                 P16: a'=[a.g0,b.g0,a.g2,b.g2], b'=[a.g1,b.g1,a.g3,b.g3]
__device__ __forceinline__ void p32(uint &a, uint &b) {
    auto r = __builtin_amdgcn_permlane32_swap(a, b, false, false);
    a = r[0]; b = r[1];
}
__device__ __forceinline__ void p16(uint &a, uint &b) {
    auto r = __builtin_amdgcn_permlane16_swap(a, b, false, false);
    a = r[0]; b = r[1];
}

// D-layout acc (4 quadrants, feature 16mt+4g+r at point c) -> next layer's
// B fragments (element e at lane g' = feature 8g'+e / 32+8g'+e), in registers.
template<bool RELU>
__device__ __forceinline__ void handoff64(const f32x4 (&a)[4], uint4 &b0, uint4 &b1) {
    uint q[4][2];
#pragma unroll
    for (int mt = 0; mt < 4; ++mt)
#pragma unroll
        for (int h = 0; h < 2; ++h) {
            float x = a[mt][2 * h], y = a[mt][2 * h + 1];
            if (RELU) { x = fmaxf(x, 0.f); y = fmaxf(y, 0.f); }
            q[mt][h] = cvt2(x, y);
        }
    uint x, y;
    x = q[0][0]; y = q[1][0]; p32(x, y); p16(x, y); b0.x = x; b0.z = y;
    x = q[0][1]; y = q[1][1]; p32(x, y); p16(x, y); b0.y = x; b0.w = y;
    x = q[2][0]; y = q[3][0]; p32(x, y); p16(x, y); b1.x = x; b1.z = y;
    x = q[2][1]; y = q[3][1]; p32(x, y); p16(x, y); b1.y = x; b1.w = y;
}

// weight element fetch with layer-specific remapping (see R1 notes).
__device__ __forceinline__ float wval(int kind, const float* W, int k, int m) {
    switch (kind) {
        default:
        case 0: return W[k * 64 + m];
        case 1: return W[k * 17 + (m == 0 ? 0 : m + 1)];
        case 2: { int r = (k >= 1 && k <= 15) ? (k + 2) : ((k >= 16 && k <= 18) ? (k - 16) : -1);
                  return (r < 0) ? 0.f : W[r * 64 + m]; }
        case 3: { int r = (k >= 1 && k <= 15) ? (k - 1) : -1;
                  return (r < 0) ? 0.f : W[r * 64 + m]; }
        case 4: return (m < 3) ? W[k * 3 + m] : 0.f;
    }
}

// ------------------- prologue: arrange weights as A-fragments -------------------
__global__ void prep_weights(Params P) {
    const int idx = blockIdx.x * 256 + threadIdx.x;   // 0 .. 27647
    const int br  = idx / 9216;
    const int rem = idx - br * 9216;
    int L, q;
    if      (rem < 1024) { L = 0; q = rem;        }
    else if (rem < 3072) { L = 1; q = rem - 1024; }
    else if (rem < 3584) { L = 2; q = rem - 3072; }
    else if (rem < 4608) { L = 3; q = rem - 3584; }
    else if (rem < 6656) { L = 4; q = rem - 4608; }
    else if (rem < 8704) { L = 5; q = rem - 6656; }
    else                 { L = 6; q = rem - 8704; }
    const float* W   = P.w[br * 7 + L];
    const int kk_n   = (L == 0 || L == 3) ? 1 : 2;
    const int kind   = (L == 2) ? 1 : (L == 3) ? (br == 0 ? 2 : 3) : (L == 6) ? 4 : 0;
    const int E  = q * 2;
    const int b  = E >> 9;
    const int ln = (E >> 3) & 63;
    const int e  = E & 7;
    const int mt = b / kk_n;
    const int kk = b - mt * kk_n;
    const int m  = mt * 16 + (ln & 15);
    const int k  = kk * 32 + (ln >> 4) * 8 + e;
    g_wbuf[idx] = cvt2(wval(kind, W, k, m), wval(kind, W, k + 1, m));
}

// hidden 64->64 layer: weights from LDS, activations register-resident
__device__ __forceinline__ void layer64(const ushort* lw, int lane,
                                        const uint4 (&b0)[NPT], const uint4 (&b1)[NPT],
                                        f32x4 (&acc)[NPT][4]) {
    bf16x8 wf[8];
#pragma unroll
    for (int b = 0; b < 8; ++b) wf[b] = *(const bf16x8*)(lw + b * 512 + lane * 8);
#pragma unroll
    for (int t = 0; t < NPT; ++t) {
        const bf16x8 i0 = __builtin_bit_cast(bf16x8, b0[t]);
        const bf16x8 i1 = __builtin_bit_cast(bf16x8, b1[t]);
#pragma unroll
        for (int mt = 0; mt < 4; ++mt) {
            f32x4 a = (f32x4){0.f, 0.f, 0.f, 0.f};
            a = MFMA(wf[mt * 2 + 0], i0, a);
            a = MFMA(wf[mt * 2 + 1], i1, a);
            acc[t][mt] = a;
        }
    }
}

__global__ __launch_bounds__(BLOCK, 4) void nerf_main(Params P) {
    __shared__ __align__(16) ushort lds_w[3 * BR_SZ];   // 108 KB weights, no act LDS

    const int tid = threadIdx.x;
    // ---- stage pre-arranged weight blob global -> LDS, once per block ----
    {
        const uint4* src = (const uint4*)g_wbuf;     // 6912 uint4
        uint4* dst = (uint4*)lds_w;
        for (int i = tid; i < 6912; i += BLOCK) dst[i] = src[i];
    }
    __syncthreads();

    const int wave = tid >> 6;
    const int lane = tid & 63;
    const int c = lane & 15;   // point within tile
    const int g = lane >> 4;   // lane group

#pragma unroll 1
    for (int ch = blockIdx.x; ch < NCHUNK; ch += gridDim.x) {
        const int p0 = ch * CHUNK + wave * (NPT * 16);

        float stot[NPT], car[NPT], cag[NPT], cab[NPT];
#pragma unroll
        for (int t = 0; t < NPT; ++t) { stot[t] = 0.f; car[t] = 0.f; cag[t] = 0.f; cab[t] = 0.f; }

#pragma unroll 1
        for (int br = 0; br < 3; ++br) {
            const ushort* lw  = lds_w + br * BR_SZ;
            const float* emb  = P.emb[br];
            const float* msk  = P.mask[br];
            float sig_pre[NPT], rp[NPT], gp[NPT], bp[NPT];
            uint4 b0[NPT], b1[NPT];
            f32x4 acc[NPT][4];

            // ---- sigma L0 : emb(32) -> 64  (B built straight from global f32)
            {
                bf16x8 wf[4];
#pragma unroll
                for (int b = 0; b < 4; ++b)
                    wf[b] = *(const bf16x8*)(lw + OFF_S0 + b * 512 + lane * 8);
#pragma unroll
                for (int t = 0; t < NPT; ++t) {
                    const float* ep = emb + (size_t)(p0 + t * 16 + c) * 32 + g * 8;
                    const float4 ea = *(const float4*)ep;
                    const float4 eb = *(const float4*)(ep + 4);
                    uint4 iv;
                    iv.x = cvt2(ea.x, ea.y); iv.y = cvt2(ea.z, ea.w);
                    iv.z = cvt2(eb.x, eb.y); iv.w = cvt2(eb.z, eb.w);
                    const bf16x8 inf = __builtin_bit_cast(bf16x8, iv);
#pragma unroll
                    for (int mt = 0; mt < 4; ++mt) {
                        f32x4 a = (f32x4){0.f, 0.f, 0.f, 0.f};
                        acc[t][mt] = MFMA(wf[mt], inf, a);
                    }
                }
            }
#pragma unroll
            for (int t = 0; t < NPT; ++t) handoff64<true>(acc[t], b0[t], b1[t]);

            // ---- sigma L1 : 64 -> 64, relu
            layer64(lw + OFF_S1, lane, b0, b1, acc);
#pragma unroll
            for (int t = 0; t < NPT; ++t) handoff64<true>(acc[t], b0[t], b1[t]);

            // ---- sigma L2 : 64 -> 16 [f0=sigma-pre, f1..15=geo], raw ----
            {
                const bf16x8 w0 = *(const bf16x8*)(lw + OFF_S2 + 0 * 512 + lane * 8);
                const bf16x8 w1 = *(const bf16x8*)(lw + OFF_S2 + 1 * 512 + lane * 8);
#pragma unroll
                for (int t = 0; t < NPT; ++t) {
                    f32x4 a = (f32x4){0.f, 0.f, 0.f, 0.f};
                    a = MFMA(w0, __builtin_bit_cast(bf16x8, b0[t]), a);
                    a = MFMA(w1, __builtin_bit_cast(bf16x8, b1[t]), a);
                    sig_pre[t] = a[0];   // feature 0 at g==0 lanes
                    // handoff16 -> C0's single B fragment (k 0..15 live, k>=16 weights are 0)
                    uint q0 = cvt2(a[0], a[1]);
                    uint q1 = cvt2(a[2], a[3]);
                    uint x = q0, y = q0;  p32(x, y);  p16(x, y);   // x=w0, y=w2
                    uint x1 = q1, y1 = q1; p32(x1, y1); p16(x1, y1); // x1=w1, y1=w3
                    if (br == 0) {  // bg: views occupy k=16..18 -> g'==2, words 0,1
                        const float* vp = P.views + (size_t)(p0 + t * 16 + c) * 3;
                        const uint vw0 = cvt2(vp[0], vp[1]);
                        const uint vw1 = cvt2(vp[2], 0.f);
                        if (g == 2) { x = vw0; x1 = vw1; }
                    }
                    b0[t] = (uint4){x, x1, y, y1};
                }
            }

            // ---- color L0 : feats[0..31] -> 64, relu (single-K MFMA)
            {
                bf16x8 wf[4];
#pragma unroll
                for (int b = 0; b < 4; ++b)
                    wf[b] = *(const bf16x8*)(lw + OFF_C0 + b * 512 + lane * 8);
#pragma unroll
                for (int t = 0; t < NPT; ++t) {
                    const bf16x8 inf = __builtin_bit_cast(bf16x8, b0[t]);
#pragma unroll
                    for (int mt = 0; mt < 4; ++mt) {
                        f32x4 a = (f32x4){0.f, 0.f, 0.f, 0.f};
                        acc[t][mt] = MFMA(wf[mt], inf, a);
                    }
                }
            }
#pragma unroll
            for (int t = 0; t < NPT; ++t) handoff64<true>(acc[t], b0[t], b1[t]);

            // ---- color L1, L2 : 64 -> 64, relu
            layer64(lw + OFF_C1, lane, b0, b1, acc);
#pragma unroll
            for (int t = 0; t < NPT; ++t) handoff64<true>(acc[t], b0[t], b1[t]);
            layer64(lw + OFF_C2, lane, b0, b1, acc);
#pragma unroll
            for (int t = 0; t < NPT; ++t) handoff64<true>(acc[t], b0[t], b1[t]);

            // ---- color L3 : 64 -> rgb (features 0..2 at g==0 lanes)
            {
                const bf16x8 w0 = *(const bf16x8*)(lw + OFF_C3 + 0 * 512 + lane * 8);
                const bf16x8 w1 = *(const bf16x8*)(lw + OFF_C3 + 1 * 512 + lane * 8);
#pragma unroll
                for (int t = 0; t < NPT; ++t) {
                    f32x4 a = (f32x4){0.f, 0.f, 0.f, 0.f};
                    a = MFMA(w0, __builtin_bit_cast(bf16x8, b0[t]), a);
                    a = MFMA(w1, __builtin_bit_cast(bf16x8, b1[t]), a);
                    rp[t] = a[0]; gp[t] = a[1]; bp[t] = a[2];
                }
            }

            // ---- branch epilogue: softplus/sigmoid/mask via v_exp/v_log/v_rcp
#pragma unroll
            for (int t = 0; t < NPT; ++t) {
                const float mk = msk[p0 + t * 16 + c];
                const float x  = sig_pre[t];
                const float ex = __expf(x);
                const float sp = (x > 15.f) ? x : 0.69314718f * __log2f(1.f + ex);
                const float sb = sp * mk;
                stot[t] += sb;
                const float sm = sb * mk;
                car[t] += sm * fast_rcp(1.f + __expf(-rp[t]));
                cag[t] += sm * fast_rcp(1.f + __expf(-gp[t]));
                cab[t] += sm * fast_rcp(1.f + __expf(-bp[t]));
            }
        }

        // ---- final blend + store (lanes 0..15 hold the per-point values)
#pragma unroll
        for (int t = 0; t < NPT; ++t) {
            if (lane < 16) {
                const float s   = stot[t] + 1e-9f;
                const float inv = fast_rcp(s);
                float4 o;
                o.x = car[t] * inv; o.y = cag[t] * inv; o.z = cab[t] * inv; o.w = s;
                *(float4*)(P.out + (size_t)(p0 + t * 16 + lane) * 4) = o;
            }
        }
    }
}

extern "C" void kernel_launch(void* const* d_in, const int* in_sizes, int n_in,
                              void* d_out, int out_size, void* d_ws, size_t ws_size,
                              hipStream_t stream) {
    (void)in_sizes; (void)n_in; (void)d_ws; (void)ws_size; (void)out_size;
    Params P;
    P.emb[0] = (const float*)d_in[0];   // embedded_xyz      (bg)
    P.emb[1] = (const float*)d_in[1];   // embedded_xyzt     (fg)
    P.emb[2] = (const float*)d_in[2];   // embedded_xyzt_cam (actor)
    P.views  = (const float*)d_in[3];
    P.mask[0] = (const float*)d_in[4];
    P.mask[1] = (const float*)d_in[5];
    P.mask[2] = (const float*)d_in[6];
    for (int i = 0; i < 21; ++i) P.w[i] = (const float*)d_in[7 + i];
    P.out = (float*)d_out;
    prep_weights<<<108, 256, 0, stream>>>(P);   // 27648 threads, one u32 word each
    nerf_main<<<GRID, BLOCK, 0, stream>>>(P);
}

// Round 9
// 157.102 us; speedup vs baseline: 1.4610x; 1.1348x over previous
//
#include <hip/hip_runtime.h>

typedef unsigned int  uint;
typedef unsigned short ushort;

#define N_PTS  1048576
#define BLOCK  1024
#define WAVES  16
#define NPT    2
#define CHUNK  (WAVES * NPT * 16)     // 512 points per block-iteration
#define NCHUNK (N_PTS / CHUNK)        // 2048, exact
#define GRID   256                    // 1 block/CU, 16 waves/CU

static_assert(N_PTS % CHUNK == 0, "chunking");
static_assert(NCHUNK % GRID == 0, "grid stride");

typedef __attribute__((ext_vector_type(8))) __bf16  bf16x8;
typedef __attribute__((ext_vector_type(2))) __bf16  bf16x2;
typedef __attribute__((ext_vector_type(4))) float   f32x4;

struct Params {
    const float* emb[3];
    const float* views;
    const float* mask[3];
    const float* w[21];
    float* out;
};

// Pre-arranged bf16 A-fragment weight blob (k-permuted), written per launch.
__device__ uint g_wbuf[3 * 9216];

// per-branch weight blob layout (u16 offsets)
#define OFF_S0 0
#define OFF_S1 2048
#define OFF_S2 6144
#define OFF_C0 7168
#define OFF_C1 9216
#define OFF_C2 13312
#define OFF_C3 17408
#define BR_SZ  18432

// f32 pair -> packed bf16x2 (compiler emits v_cvt_pk_bf16_f32, RNE)
__device__ __forceinline__ uint cvt2(float a, float b) {
    bf16x2 v = {(__bf16)a, (__bf16)b};
    return __builtin_bit_cast(uint, v);
}

__device__ __forceinline__ f32x4 MFMA(bf16x8 a, bf16x8 b, f32x4 c) {
    return __builtin_amdgcn_mfma_f32_16x16x32_bf16(a, b, c, 0, 0, 0);
}

__device__ __forceinline__ float fast_rcp(float x) { return __builtin_amdgcn_rcpf(x); }

// Weight value at PHYSICAL k-slot kp, output col m, with the k-permutation
// k̃ = 32*(mt>>1) + 8g + 4*(mt&1) + r  inverted:  f = 16*((e>>2)+2h) + 4g + (e&3).
// Layers: 0=S0(identity,32x64) 1=S1 2=S2(64x17,col-remap) 3=C0(K=32,geo+views)
//         4=C1 5=C2 6=C3(64x3)
__device__ __forceinline__ float wphys(int L, int br, const float* W, int kp, int m) {
    if (L == 0) return W[kp * 64 + m];                    // S0: inputs from global
    const int g = (kp & 31) >> 3, e = kp & 7, h = kp >> 5;
    if (L == 3) {                                         // C0: K=32 handoff16 + views
        if (e < 4) {
            const int f = 4 * g + e;                      // S2-output feature (0=sigma)
            if (f < 1) return 0.f;
            return (br == 0) ? W[(f + 2) * 64 + m] : W[(f - 1) * 64 + m];
        }
        return (br == 0 && g == 0 && e <= 6) ? W[(e - 4) * 64 + m] : 0.f;
    }
    const int f = 16 * ((e >> 2) + 2 * h) + 4 * g + (e & 3);
    if (L == 2) return W[f * 17 + (m == 0 ? 0 : m + 1)];  // S2: m0=sigma, m>=1=geo m-1
    if (L == 6) return (m < 3) ? W[f * 3 + m] : 0.f;      // C3: rgb
    return W[f * 64 + m];                                  // S1,C1,C2: 64x64
}

// ------------------- prologue: arrange weights as A-fragments -------------------
__global__ void prep_weights(Params P) {
    const int idx = blockIdx.x * 256 + threadIdx.x;   // 0 .. 27647
    const int br  = idx / 9216;
    const int rem = idx - br * 9216;
    int L, q;
    if      (rem < 1024) { L = 0; q = rem;        }
    else if (rem < 3072) { L = 1; q = rem - 1024; }
    else if (rem < 3584) { L = 2; q = rem - 3072; }
    else if (rem < 4608) { L = 3; q = rem - 3584; }
    else if (rem < 6656) { L = 4; q = rem - 4608; }
    else if (rem < 8704) { L = 5; q = rem - 6656; }
    else                 { L = 6; q = rem - 8704; }
    const float* W   = P.w[br * 7 + L];
    const int kk_n   = (L == 0 || L == 3) ? 1 : 2;
    const int E  = q * 2;            // u16 element index within layer blob (even)
    const int b  = E >> 9;           // 512-elem fragment block
    const int ln = (E >> 3) & 63;    // lane within block
    const int e  = E & 7;            // element within lane (even)
    const int mt = b / kk_n;
    const int kk = b - mt * kk_n;
    const int m  = mt * 16 + (ln & 15);
    const int kp = kk * 32 + (ln >> 4) * 8 + e;   // physical k-slot
    g_wbuf[idx] = cvt2(wphys(L, br, W, kp, m), wphys(L, br, W, kp + 1, m));
}

// D-layout acc -> next layer's B fragments, PURE in-lane (weights k-permuted):
// feature 16mt+4g+r  ->  k̃ = 32*(mt>>1) + 8g + 4*(mt&1) + r   (same lane group g)
template<bool RELU>
__device__ __forceinline__ void handoff64(const f32x4 (&a)[4], uint4 &b0, uint4 &b1) {
#pragma unroll
    for (int h = 0; h < 2; ++h) {
        const f32x4 &lo = a[2 * h], &hi = a[2 * h + 1];
        float v[8] = {lo[0], lo[1], lo[2], lo[3], hi[0], hi[1], hi[2], hi[3]};
        if (RELU) {
#pragma unroll
            for (int i = 0; i < 8; ++i) v[i] = fmaxf(v[i], 0.f);
        }
        uint4 &b = h ? b1 : b0;
        b.x = cvt2(v[0], v[1]); b.y = cvt2(v[2], v[3]);
        b.z = cvt2(v[4], v[5]); b.w = cvt2(v[6], v[7]);
    }
}

// hidden 64->64 layer: weights from LDS, activations register-resident
__device__ __forceinline__ void layer64(const ushort* lw, int lane,
                                        const uint4 (&b0)[NPT], const uint4 (&b1)[NPT],
                                        f32x4 (&acc)[NPT][4]) {
    bf16x8 wf[8];
#pragma unroll
    for (int b = 0; b < 8; ++b) wf[b] = *(const bf16x8*)(lw + b * 512 + lane * 8);
#pragma unroll
    for (int t = 0; t < NPT; ++t) {
        const bf16x8 i0 = __builtin_bit_cast(bf16x8, b0[t]);
        const bf16x8 i1 = __builtin_bit_cast(bf16x8, b1[t]);
#pragma unroll
        for (int mt = 0; mt < 4; ++mt) {
            f32x4 a = (f32x4){0.f, 0.f, 0.f, 0.f};
            a = MFMA(wf[mt * 2 + 0], i0, a);
            a = MFMA(wf[mt * 2 + 1], i1, a);
            acc[t][mt] = a;
        }
    }
}

__global__ __launch_bounds__(BLOCK, 4) void nerf_main(Params P) {
    __shared__ __align__(16) ushort lds_w[3 * BR_SZ];   // 108 KB weights, no act LDS

    const int tid = threadIdx.x;
    // ---- stage pre-arranged weight blob global -> LDS, once per block ----
    {
        const uint4* src = (const uint4*)g_wbuf;     // 6912 uint4
        uint4* dst = (uint4*)lds_w;
        for (int i = tid; i < 6912; i += BLOCK) dst[i] = src[i];
    }
    __syncthreads();

    const int wave = tid >> 6;
    const int lane = tid & 63;
    const int c = lane & 15;   // point within tile
    const int g = lane >> 4;   // lane group

#pragma unroll 1
    for (int ch = blockIdx.x; ch < NCHUNK; ch += gridDim.x) {
        const int p0 = ch * CHUNK + wave * (NPT * 16);

        float stot[NPT], car[NPT], cag[NPT], cab[NPT];
#pragma unroll
        for (int t = 0; t < NPT; ++t) { stot[t] = 0.f; car[t] = 0.f; cag[t] = 0.f; cab[t] = 0.f; }

#pragma unroll 1
        for (int br = 0; br < 3; ++br) {
            const ushort* lw  = lds_w + br * BR_SZ;
            const float* emb  = P.emb[br];
            const float* msk  = P.mask[br];
            float sig_pre[NPT], rp[NPT], gp[NPT], bp[NPT];
            uint4 b0[NPT], b1[NPT];
            f32x4 acc[NPT][4];

            // ---- sigma L0 : emb(32) -> 64  (B built straight from global f32)
            {
                bf16x8 wf[4];
#pragma unroll
                for (int b = 0; b < 4; ++b)
                    wf[b] = *(const bf16x8*)(lw + OFF_S0 + b * 512 + lane * 8);
#pragma unroll
                for (int t = 0; t < NPT; ++t) {
                    const float* ep = emb + (size_t)(p0 + t * 16 + c) * 32 + g * 8;
                    const float4 ea = *(const float4*)ep;
                    const float4 eb = *(const float4*)(ep + 4);
                    uint4 iv;
                    iv.x = cvt2(ea.x, ea.y); iv.y = cvt2(ea.z, ea.w);
                    iv.z = cvt2(eb.x, eb.y); iv.w = cvt2(eb.z, eb.w);
                    const bf16x8 inf = __builtin_bit_cast(bf16x8, iv);
#pragma unroll
                    for (int mt = 0; mt < 4; ++mt) {
                        f32x4 a = (f32x4){0.f, 0.f, 0.f, 0.f};
                        acc[t][mt] = MFMA(wf[mt], inf, a);
                    }
                }
            }
#pragma unroll
            for (int t = 0; t < NPT; ++t) handoff64<true>(acc[t], b0[t], b1[t]);

            // ---- sigma L1 : 64 -> 64, relu
            layer64(lw + OFF_S1, lane, b0, b1, acc);
#pragma unroll
            for (int t = 0; t < NPT; ++t) handoff64<true>(acc[t], b0[t], b1[t]);

            // ---- sigma L2 : 64 -> 16 [f0=sigma-pre, f1..15=geo], raw ----
            {
                const bf16x8 w0 = *(const bf16x8*)(lw + OFF_S2 + 0 * 512 + lane * 8);
                const bf16x8 w1 = *(const bf16x8*)(lw + OFF_S2 + 1 * 512 + lane * 8);
#pragma unroll
                for (int t = 0; t < NPT; ++t) {
                    f32x4 a = (f32x4){0.f, 0.f, 0.f, 0.f};
                    a = MFMA(w0, __builtin_bit_cast(bf16x8, b0[t]), a);
                    a = MFMA(w1, __builtin_bit_cast(bf16x8, b1[t]), a);
                    sig_pre[t] = a[0];   // feature 0, valid at g==0 (lanes 0..15)
                    // in-lane handoff16 -> C0 B-fragment (features 4g+r at e=0..3)
                    uint4 nb;
                    nb.x = cvt2(a[0], a[1]);
                    nb.y = cvt2(a[2], a[3]);
                    nb.z = 0u; nb.w = 0u;
                    if (br == 0 && g == 0) {   // views at k̃=4,5,6 (g==0, e=4..6)
                        const float* vp = P.views + (size_t)(p0 + t * 16 + c) * 3;
                        nb.z = cvt2(vp[0], vp[1]);
                        nb.w = cvt2(vp[2], 0.f);
                    }
                    b0[t] = nb;
                }
            }

            // ---- color L0 : feats -> 64, relu (single-K MFMA, K=32)
            {
                bf16x8 wf[4];
#pragma unroll
                for (int b = 0; b < 4; ++b)
                    wf[b] = *(const bf16x8*)(lw + OFF_C0 + b * 512 + lane * 8);
#pragma unroll
                for (int t = 0; t < NPT; ++t) {
                    const bf16x8 inf = __builtin_bit_cast(bf16x8, b0[t]);
#pragma unroll
                    for (int mt = 0; mt < 4; ++mt) {
                        f32x4 a = (f32x4){0.f, 0.f, 0.f, 0.f};
                        acc[t][mt] = MFMA(wf[mt], inf, a);
                    }
                }
            }
#pragma unroll
            for (int t = 0; t < NPT; ++t) handoff64<true>(acc[t], b0[t], b1[t]);

            // ---- color L1, L2 : 64 -> 64, relu
            layer64(lw + OFF_C1, lane, b0, b1, acc);
#pragma unroll
            for (int t = 0; t < NPT; ++t) handoff64<true>(acc[t], b0[t], b1[t]);
            layer64(lw + OFF_C2, lane, b0, b1, acc);
#pragma unroll
            for (int t = 0; t < NPT; ++t) handoff64<true>(acc[t], b0[t], b1[t]);

            // ---- color L3 : 64 -> rgb (features 0..2 at g==0 lanes)
            {
                const bf16x8 w0 = *(const bf16x8*)(lw + OFF_C3 + 0 * 512 + lane * 8);
                const bf16x8 w1 = *(const bf16x8*)(lw + OFF_C3 + 1 * 512 + lane * 8);
#pragma unroll
                for (int t = 0; t < NPT; ++t) {
                    f32x4 a = (f32x4){0.f, 0.f, 0.f, 0.f};
                    a = MFMA(w0, __builtin_bit_cast(bf16x8, b0[t]), a);
                    a = MFMA(w1, __builtin_bit_cast(bf16x8, b1[t]), a);
                    rp[t] = a[0]; gp[t] = a[1]; bp[t] = a[2];
                }
            }

            // ---- branch epilogue: softplus/sigmoid/mask via v_exp/v_log/v_rcp
#pragma unroll
            for (int t = 0; t < NPT; ++t) {
                const float mk = msk[p0 + t * 16 + c];
                const float x  = sig_pre[t];
                const float ex = __expf(x);
                const float sp = (x > 15.f) ? x : 0.69314718f * __log2f(1.f + ex);
                const float sb = sp * mk;
                stot[t] += sb;
                const float sm = sb * mk;
                car[t] += sm * fast_rcp(1.f + __expf(-rp[t]));
                cag[t] += sm * fast_rcp(1.f + __expf(-gp[t]));
                cab[t] += sm * fast_rcp(1.f + __expf(-bp[t]));
            }
        }

        // ---- final blend + store (lanes 0..15 hold the per-point values)
#pragma unroll
        for (int t = 0; t < NPT; ++t) {
            if (lane < 16) {
                const float s   = stot[t] + 1e-9f;
                const float inv = fast_rcp(s);
                float4 o;
                o.x = car[t] * inv; o.y = cag[t] * inv; o.z = cab[t] * inv; o.w = s;
                *(float4*)(P.out + (size_t)(p0 + t * 16 + lane) * 4) = o;
            }
        }
    }
}

extern "C" void kernel_launch(void* const* d_in, const int* in_sizes, int n_in,
                              void* d_out, int out_size, void* d_ws, size_t ws_size,
                              hipStream_t stream) {
    (void)in_sizes; (void)n_in; (void)d_ws; (void)ws_size; (void)out_size;
    Params P;
    P.emb[0] = (const float*)d_in[0];   // embedded_xyz      (bg)
    P.emb[1] = (const float*)d_in[1];   // embedded_xyzt     (fg)
    P.emb[2] = (const float*)d_in[2];   // embedded_xyzt_cam (actor)
    P.views  = (const float*)d_in[3];
    P.mask[0] = (const float*)d_in[4];
    P.mask[1] = (const float*)d_in[5];
    P.mask[2] = (const float*)d_in[6];
    for (int i = 0; i < 21; ++i) P.w[i] = (const float*)d_in[7 + i];
    P.out = (float*)d_out;
    prep_weights<<<108, 256, 0, stream>>>(P);   // 27648 threads, one u32 word each
    nerf_main<<<GRID, BLOCK, 0, stream>>>(P);
}

// Round 11
// 130.408 us; speedup vs baseline: 1.7601x; 1.2047x over previous
//
#include <hip/hip_runtime.h>

typedef unsigned int  uint;
typedef unsigned short ushort;

#define N_PTS  1048576
#define BLOCK  1024
#define WAVES  16
#define NPT    2
#define CHUNK  (WAVES * NPT * 16)     // 512 points per block-iteration
#define NCHUNK (N_PTS / CHUNK)        // 2048, exact
#define GRID   256                    // 1 block/CU, 16 waves/CU

static_assert(N_PTS % CHUNK == 0, "chunking");
static_assert(NCHUNK % GRID == 0, "grid stride");

typedef __attribute__((ext_vector_type(8))) _Float16 f16x8;
typedef __attribute__((ext_vector_type(2))) _Float16 f16x2;
typedef __attribute__((ext_vector_type(4))) float    f32x4;

struct Params {
    const float* emb[3];
    const float* views;
    const float* mask[3];
    const float* w[21];
    float* out;
};

// Pre-arranged f16 A-fragment weight blob (k-permuted), written per launch.
__device__ uint g_wbuf[3 * 9216];

// per-branch weight blob layout (u16 offsets)
#define OFF_S0 0
#define OFF_S1 2048
#define OFF_S2 6144
#define OFF_C0 7168
#define OFF_C1 9216
#define OFF_C2 13312
#define OFF_C3 17408
#define BR_SZ  18432

// f32 pair -> packed f16x2, RNE (for weights; prep-time only)
__device__ __forceinline__ uint cvt2w(float a, float b) {
    f16x2 v = {(_Float16)a, (_Float16)b};
    return __builtin_bit_cast(uint, v);
}
// f32 pair -> packed f16x2 via v_cvt_pkrtz_f16_f32 (hot path)
__device__ __forceinline__ uint cvt2(float a, float b) {
    return __builtin_bit_cast(uint, __builtin_amdgcn_cvt_pkrtz(a, b));
}
// packed relu: v_pk_max_f16 with +0  (elementwise_max on <2 x half>)
__device__ __forceinline__ uint maxz(uint x) {
    f16x2 v = __builtin_bit_cast(f16x2, x);
    f16x2 z = {(_Float16)0.f, (_Float16)0.f};
    return __builtin_bit_cast(uint, __builtin_elementwise_max(v, z));
}

__device__ __forceinline__ f32x4 MFMA(f16x8 a, f16x8 b, f32x4 c) {
    return __builtin_amdgcn_mfma_f32_16x16x32_f16(a, b, c, 0, 0, 0);
}

__device__ __forceinline__ float fast_rcp(float x) { return __builtin_amdgcn_rcpf(x); }

// Weight value at PHYSICAL k-slot kp, output col m, with the k-permutation
// k̃ = 32*(mt>>1) + 8g + 4*(mt&1) + r  inverted:  f = 16*((e>>2)+2h) + 4g + (e&3).
// Layers: 0=S0(identity,32x64) 1=S1 2=S2(64x17,col-remap) 3=C0(K=32,geo+views)
//         4=C1 5=C2 6=C3(64x3)
__device__ __forceinline__ float wphys(int L, int br, const float* W, int kp, int m) {
    if (L == 0) return W[kp * 64 + m];                    // S0: inputs from global
    const int g = (kp & 31) >> 3, e = kp & 7, h = kp >> 5;
    if (L == 3) {                                         // C0: K=32 handoff16 + views
        if (e < 4) {
            const int f = 4 * g + e;                      // S2-output feature (0=sigma)
            if (f < 1) return 0.f;
            return (br == 0) ? W[(f + 2) * 64 + m] : W[(f - 1) * 64 + m];
        }
        return (br == 0 && g == 0 && e <= 6) ? W[(e - 4) * 64 + m] : 0.f;
    }
    const int f = 16 * ((e >> 2) + 2 * h) + 4 * g + (e & 3);
    if (L == 2) return W[f * 17 + (m == 0 ? 0 : m + 1)];  // S2: m0=sigma, m>=1=geo m-1
    if (L == 6) return (m < 3) ? W[f * 3 + m] : 0.f;      // C3: rgb
    return W[f * 64 + m];                                  // S1,C1,C2: 64x64
}

// ------------------- prologue: arrange weights as A-fragments -------------------
__global__ void prep_weights(Params P) {
    const int idx = blockIdx.x * 256 + threadIdx.x;   // 0 .. 27647
    const int br  = idx / 9216;
    const int rem = idx - br * 9216;
    int L, q;
    if      (rem < 1024) { L = 0; q = rem;        }
    else if (rem < 3072) { L = 1; q = rem - 1024; }
    else if (rem < 3584) { L = 2; q = rem - 3072; }
    else if (rem < 4608) { L = 3; q = rem - 3584; }
    else if (rem < 6656) { L = 4; q = rem - 4608; }
    else if (rem < 8704) { L = 5; q = rem - 6656; }
    else                 { L = 6; q = rem - 8704; }
    const float* W   = P.w[br * 7 + L];
    const int kk_n   = (L == 0 || L == 3) ? 1 : 2;
    const int E  = q * 2;            // u16 element index within layer blob (even)
    const int b  = E >> 9;           // 512-elem fragment block
    const int ln = (E >> 3) & 63;    // lane within block
    const int e  = E & 7;            // element within lane (even)
    const int mt = b / kk_n;
    const int kk = b - mt * kk_n;
    const int m  = mt * 16 + (ln & 15);
    const int kp = kk * 32 + (ln >> 4) * 8 + e;   // physical k-slot
    g_wbuf[idx] = cvt2w(wphys(L, br, W, kp, m), wphys(L, br, W, kp + 1, m));
}

// D-layout acc -> next layer's B fragments, PURE in-lane (weights k-permuted):
// feature 16mt+4g+r  ->  k̃ = 32*(mt>>1) + 8g + 4*(mt&1) + r   (same lane group g)
template<bool RELU>
__device__ __forceinline__ void handoff64(const f32x4 (&a)[4], uint4 &b0, uint4 &b1) {
#pragma unroll
    for (int h = 0; h < 2; ++h) {
        const f32x4 &lo = a[2 * h], &hi = a[2 * h + 1];
        uint w0 = cvt2(lo[0], lo[1]);
        uint w1 = cvt2(lo[2], lo[3]);
        uint w2 = cvt2(hi[0], hi[1]);
        uint w3 = cvt2(hi[2], hi[3]);
        if (RELU) { w0 = maxz(w0); w1 = maxz(w1); w2 = maxz(w2); w3 = maxz(w3); }
        uint4 &b = h ? b1 : b0;
        b.x = w0; b.y = w1; b.z = w2; b.w = w3;
    }
}

// hidden 64->64 layer: weights from LDS, activations register-resident
__device__ __forceinline__ void layer64(const ushort* lw, int lane,
                                        const uint4 (&b0)[NPT], const uint4 (&b1)[NPT],
                                        f32x4 (&acc)[NPT][4]) {
    f16x8 wf[8];
#pragma unroll
    for (int b = 0; b < 8; ++b) wf[b] = *(const f16x8*)(lw + b * 512 + lane * 8);
#pragma unroll
    for (int t = 0; t < NPT; ++t) {
        const f16x8 i0 = __builtin_bit_cast(f16x8, b0[t]);
        const f16x8 i1 = __builtin_bit_cast(f16x8, b1[t]);
#pragma unroll
        for (int mt = 0; mt < 4; ++mt) {
            f32x4 a = (f32x4){0.f, 0.f, 0.f, 0.f};
            a = MFMA(wf[mt * 2 + 0], i0, a);
            a = MFMA(wf[mt * 2 + 1], i1, a);
            acc[t][mt] = a;
        }
    }
}

__global__ __launch_bounds__(BLOCK, 4) void nerf_main(Params P) {
    __shared__ __align__(16) ushort lds_w[3 * BR_SZ];   // 108 KB weights, no act LDS

    const int tid = threadIdx.x;
    // ---- stage pre-arranged weight blob global -> LDS, once per block ----
    {
        const uint4* src = (const uint4*)g_wbuf;     // 6912 uint4
        uint4* dst = (uint4*)lds_w;
        for (int i = tid; i < 6912; i += BLOCK) dst[i] = src[i];
    }
    __syncthreads();

    const int wave = tid >> 6;
    const int lane = tid & 63;
    const int c = lane & 15;   // point within tile
    const int g = lane >> 4;   // lane group

#pragma unroll 1
    for (int ch = blockIdx.x; ch < NCHUNK; ch += gridDim.x) {
        const int p0 = ch * CHUNK + wave * (NPT * 16);

        float stot[NPT], car[NPT], cag[NPT], cab[NPT];
#pragma unroll
        for (int t = 0; t < NPT; ++t) { stot[t] = 0.f; car[t] = 0.f; cag[t] = 0.f; cab[t] = 0.f; }

#pragma unroll 1
        for (int br = 0; br < 3; ++br) {
            const ushort* lw  = lds_w + br * BR_SZ;
            const float* emb  = P.emb[br];
            const float* msk  = P.mask[br];
            float sig_pre[NPT], rp[NPT], gp[NPT], bp[NPT];
            uint4 b0[NPT], b1[NPT];
            f32x4 acc[NPT][4];

            // ---- sigma L0 : emb(32) -> 64  (B built straight from global f32)
            {
                f16x8 wf[4];
#pragma unroll
                for (int b = 0; b < 4; ++b)
                    wf[b] = *(const f16x8*)(lw + OFF_S0 + b * 512 + lane * 8);
#pragma unroll
                for (int t = 0; t < NPT; ++t) {
                    const float* ep = emb + (size_t)(p0 + t * 16 + c) * 32 + g * 8;
                    const float4 ea = *(const float4*)ep;
                    const float4 eb = *(const float4*)(ep + 4);
                    uint4 iv;
                    iv.x = cvt2(ea.x, ea.y); iv.y = cvt2(ea.z, ea.w);
                    iv.z = cvt2(eb.x, eb.y); iv.w = cvt2(eb.z, eb.w);
                    const f16x8 inf = __builtin_bit_cast(f16x8, iv);
#pragma unroll
                    for (int mt = 0; mt < 4; ++mt) {
                        f32x4 a = (f32x4){0.f, 0.f, 0.f, 0.f};
                        acc[t][mt] = MFMA(wf[mt], inf, a);
                    }
                }
            }
#pragma unroll
            for (int t = 0; t < NPT; ++t) handoff64<true>(acc[t], b0[t], b1[t]);

            // ---- sigma L1 : 64 -> 64, relu
            layer64(lw + OFF_S1, lane, b0, b1, acc);
#pragma unroll
            for (int t = 0; t < NPT; ++t) handoff64<true>(acc[t], b0[t], b1[t]);

            // ---- sigma L2 : 64 -> 16 [f0=sigma-pre, f1..15=geo], raw ----
            {
                const f16x8 w0 = *(const f16x8*)(lw + OFF_S2 + 0 * 512 + lane * 8);
                const f16x8 w1 = *(const f16x8*)(lw + OFF_S2 + 1 * 512 + lane * 8);
#pragma unroll
                for (int t = 0; t < NPT; ++t) {
                    f32x4 a = (f32x4){0.f, 0.f, 0.f, 0.f};
                    a = MFMA(w0, __builtin_bit_cast(f16x8, b0[t]), a);
                    a = MFMA(w1, __builtin_bit_cast(f16x8, b1[t]), a);
                    sig_pre[t] = a[0];   // feature 0, valid at g==0 (lanes 0..15)
                    // in-lane handoff16 -> C0 B-fragment (features 4g+r at e=0..3)
                    uint4 nb;
                    nb.x = cvt2(a[0], a[1]);
                    nb.y = cvt2(a[2], a[3]);
                    nb.z = 0u; nb.w = 0u;
                    if (br == 0 && g == 0) {   // views at k̃=4,5,6 (g==0, e=4..6)
                        const float* vp = P.views + (size_t)(p0 + t * 16 + c) * 3;
                        nb.z = cvt2(vp[0], vp[1]);
                        nb.w = cvt2(vp[2], 0.f);
                    }
                    b0[t] = nb;
                }
            }

            // ---- color L0 : feats -> 64, relu (single-K MFMA, K=32)
            {
                f16x8 wf[4];
#pragma unroll
                for (int b = 0; b < 4; ++b)
                    wf[b] = *(const f16x8*)(lw + OFF_C0 + b * 512 + lane * 8);
#pragma unroll
                for (int t = 0; t < NPT; ++t) {
                    const f16x8 inf = __builtin_bit_cast(f16x8, b0[t]);
#pragma unroll
                    for (int mt = 0; mt < 4; ++mt) {
                        f32x4 a = (f32x4){0.f, 0.f, 0.f, 0.f};
                        acc[t][mt] = MFMA(wf[mt], inf, a);
                    }
                }
            }
#pragma unroll
            for (int t = 0; t < NPT; ++t) handoff64<true>(acc[t], b0[t], b1[t]);

            // ---- color L1, L2 : 64 -> 64, relu
            layer64(lw + OFF_C1, lane, b0, b1, acc);
#pragma unroll
            for (int t = 0; t < NPT; ++t) handoff64<true>(acc[t], b0[t], b1[t]);
            layer64(lw + OFF_C2, lane, b0, b1, acc);
#pragma unroll
            for (int t = 0; t < NPT; ++t) handoff64<true>(acc[t], b0[t], b1[t]);

            // ---- color L3 : 64 -> rgb (features 0..2 at g==0 lanes)
            {
                const f16x8 w0 = *(const f16x8*)(lw + OFF_C3 + 0 * 512 + lane * 8);
                const f16x8 w1 = *(const f16x8*)(lw + OFF_C3 + 1 * 512 + lane * 8);
#pragma unroll
                for (int t = 0; t < NPT; ++t) {
                    f32x4 a = (f32x4){0.f, 0.f, 0.f, 0.f};
                    a = MFMA(w0, __builtin_bit_cast(f16x8, b0[t]), a);
                    a = MFMA(w1, __builtin_bit_cast(f16x8, b1[t]), a);
                    rp[t] = a[0]; gp[t] = a[1]; bp[t] = a[2];
                }
            }

            // ---- branch epilogue: softplus/sigmoid/mask via v_exp/v_log/v_rcp
#pragma unroll
            for (int t = 0; t < NPT; ++t) {
                const float mk = msk[p0 + t * 16 + c];
                const float x  = sig_pre[t];
                const float ex = __expf(x);
                const float sp = (x > 15.f) ? x : 0.69314718f * __log2f(1.f + ex);
                const float sb = sp * mk;
                stot[t] += sb;
                const float sm = sb * mk;
                car[t] += sm * fast_rcp(1.f + __expf(-rp[t]));
                cag[t] += sm * fast_rcp(1.f + __expf(-gp[t]));
                cab[t] += sm * fast_rcp(1.f + __expf(-bp[t]));
            }
        }

        // ---- final blend + store (lanes 0..15 hold the per-point values)
#pragma unroll
        for (int t = 0; t < NPT; ++t) {
            if (lane < 16) {
                const float s   = stot[t] + 1e-9f;
                const float inv = fast_rcp(s);
                float4 o;
                o.x = car[t] * inv; o.y = cag[t] * inv; o.z = cab[t] * inv; o.w = s;
                *(float4*)(P.out + (size_t)(p0 + t * 16 + lane) * 4) = o;
            }
        }
    }
}

extern "C" void kernel_launch(void* const* d_in, const int* in_sizes, int n_in,
                              void* d_out, int out_size, void* d_ws, size_t ws_size,
                              hipStream_t stream) {
    (void)in_sizes; (void)n_in; (void)d_ws; (void)ws_size; (void)out_size;
    Params P;
    P.emb[0] = (const float*)d_in[0];   // embedded_xyz      (bg)
    P.emb[1] = (const float*)d_in[1];   // embedded_xyzt     (fg)
    P.emb[2] = (const float*)d_in[2];   // embedded_xyzt_cam (actor)
    P.views  = (const float*)d_in[3];
    P.mask[0] = (const float*)d_in[4];
    P.mask[1] = (const float*)d_in[5];
    P.mask[2] = (const float*)d_in[6];
    for (int i = 0; i < 21; ++i) P.w[i] = (const float*)d_in[7 + i];
    P.out = (float*)d_out;
    prep_weights<<<108, 256, 0, stream>>>(P);   // 27648 threads, one u32 word each
    nerf_main<<<GRID, BLOCK, 0, stream>>>(P);
}